// Round 8
// baseline (285.657 us; speedup 1.0000x reference)
//
#include <hip/hip_runtime.h>
#include <cstddef>

// HVAE tree decoder, fused single kernel. Round 8: phase-split GRU.
// Grid = 256 (1 block/CU), block = 512 thr (8 waves) = 64 batch rows; wave w
// owns one 16-col nt-tile of N=128 across four 16-row tiles (green r7).
// New: the 48 h-dependent gru MFMAs (h@wh for r/z/n gates) are hoisted into
// the pred phase (they only need hcur); accumulators t2/rr/rz live across the
// barrier; after the sync only the 12 x-dependent MFMAs + epilogue remain.
// Packs ~3x more independent work per barrier-to-barrier phase -> hides the
// LDS/L2 latency that made each node cost 15.8K cyc at 40% VALU / 17% MFMA.
// tanh via 1-2*rcp(e^{2x}+1): 5 ops, no select, inf-safe both tails.
// No inline asm (cvt_pk NaN'd r1/r2); scalar f2bf stores; z as f32 in-root;
// rcp activations; biases pre-summed in LDS (all green r3-r7).
// SH/PSLD must be multiples of 8 shorts (16 B): frag loads are ds_read_b128.

#define BB   16384
#define HH   128
#define OO   32
#define ROWS 64

typedef __attribute__((ext_vector_type(8))) short bf8;
typedef __attribute__((ext_vector_type(4))) float f4;

#define MFMA(a, b, c) __builtin_amdgcn_mfma_f32_16x16x32_bf16(a, b, c, 0, 0, 0)

// packed-weight offsets in ws (shorts)
#define PW_Z2H 0         // [64x128]  -> 8192
#define PW_AWI 8192      // [96x128]  -> 12288
#define PW_AWH 20480     // [384x128] -> 49152
#define PW_FWI 69632     // [96x128]  -> 12288
#define PW_FWH 81920     // [384x128] -> 49152
#define PW_UA  131072    // [128x128] -> 16384
#define PW_UF  147456    // [128x128] -> 16384
#define PW_H2O 163840    // [128x32]  -> 4096
#define PW_END 167936

#define SH   136   // LDS h row stride (shorts): 272B rows (16B-aligned)
#define PSLD 40    // LDS probs row stride (shorts): 80B rows (16B-aligned)

// bias LDS layout (floats)
#define BA_RZ  0      // abi[0..255]+abh[0..255] (r at +0, z at +128)
#define BA_BH2 256    // abh gate2
#define BA_BI2 384    // abi gate2
#define BF_RZ  512
#define BF_BH2 768
#define BF_BI2 896
#define BU     1024   // uab+ufb
#define BZ2H   1152
#define BH2O   1280   // 32
#define BIAS_N 1312

__device__ __forceinline__ short f2bf(float f) {
  union { float f; unsigned u; } v; v.f = f;
  unsigned r = v.u + 0x7fff + ((v.u >> 16) & 1);   // RNE
  return (short)(r >> 16);
}
__device__ __forceinline__ float bf2f(short h) {
  union { unsigned u; float f; } v;
  v.u = ((unsigned)(unsigned short)h) << 16;
  return v.f;
}
__device__ __forceinline__ float rcp_(float x) { return __builtin_amdgcn_rcpf(x); }
__device__ __forceinline__ float sigmoidf_(float x) { return rcp_(1.0f + __expf(-x)); }
// tanh = 1 - 2/(e^{2x}+1): x>=44 -> e=inf -> rcp=0 -> 1; x<<0 -> e=0 -> -1.
__device__ __forceinline__ float tanhf_(float x) {
  const float e = __expf(2.0f * x);
  return 1.0f - 2.0f * rcp_(e + 1.0f);
}

// ---------------- repack: fp32 [K][N] -> B-frag-major bf16 -------------------
// P[((nt*KC + kc)*64 + lane)*8 + j] = W[kc*32 + (lane>>4)*8 + j][nt*16 + (lane&15)]
template <int K, int N>
__device__ __forceinline__ void repack_one(const float* __restrict__ W,
                                           short* __restrict__ P, int idx) {
  const int KC = K / 32;
  const int j = idx & 7, lane = (idx >> 3) & 63, rest = idx >> 9;
  const int kc = rest % KC, nt = rest / KC;
  const int k = kc * 32 + ((lane >> 4) << 3) + j;
  const int n = nt * 16 + (lane & 15);
  P[idx] = f2bf(W[(size_t)k * N + n]);
}

__global__ __launch_bounds__(256) void k_repack(
    const float* __restrict__ z2hw, const float* __restrict__ awi,
    const float* __restrict__ awh, const float* __restrict__ fwi,
    const float* __restrict__ fwh, const float* __restrict__ uaw,
    const float* __restrict__ ufw, const float* __restrict__ h2ow,
    short* __restrict__ ws) {
  const int t = blockIdx.x * 256 + threadIdx.x;
  if (t < PW_AWI)        repack_one<64, 128>(z2hw, ws + PW_Z2H, t - PW_Z2H);
  else if (t < PW_AWH)   repack_one<96, 128>(awi, ws + PW_AWI, t - PW_AWI);
  else if (t < PW_FWI)   repack_one<384, 128>(awh, ws + PW_AWH, t - PW_AWH);
  else if (t < PW_FWH)   repack_one<96, 128>(fwi, ws + PW_FWI, t - PW_FWI);
  else if (t < PW_UA)    repack_one<384, 128>(fwh, ws + PW_FWH, t - PW_FWH);
  else if (t < PW_UF)    repack_one<128, 128>(uaw, ws + PW_UA, t - PW_UA);
  else if (t < PW_H2O)   repack_one<128, 128>(ufw, ws + PW_UF, t - PW_UF);
  else if (t < PW_END)   repack_one<128, 32>(h2ow, ws + PW_H2O, t - PW_H2O);
}

// ---------------- slice helpers (wave w owns nt tile w; 4 row-tiles) ---------
__device__ __forceinline__ void store_slice(const f4* hv, short* dst, int lane, int w) {
  const int l15 = lane & 15, q = lane >> 4;
#pragma unroll
  for (int rt = 0; rt < 4; ++rt)
#pragma unroll
    for (int j = 0; j < 4; ++j)
      dst[(rt * 16 + q * 4 + j) * SH + w * 16 + l15] = f2bf(hv[rt][j]);
}

// GRU h-part: accumulate bh-biases + h@wh for all three gates (48 MFMAs).
// Depends ONLY on hsrc -> can run before the probs are ready.
__device__ __forceinline__ void gru_hpart(const short* hsrc, const short* whP,
                                          const float* brz, const float* bh2v,
                                          int lane, int w,
                                          f4* t2, f4* rr, f4* rz) {
  const int l15 = lane & 15, q = lane >> 4;
  const int col = w * 16 + l15;
  bf8 ah[4][4];
#pragma unroll
  for (int rt = 0; rt < 4; ++rt)
#pragma unroll
    for (int c = 0; c < 4; ++c)
      ah[rt][c] = *(const bf8*)(hsrc + (rt * 16 + l15) * SH + c * 32 + q * 8);
  const bf8* wh = (const bf8*)whP;
  {
    const float b = bh2v[col];
#pragma unroll
    for (int rt = 0; rt < 4; ++rt) t2[rt] = (f4){b, b, b, b};
  }
  {
    const float b = brz[col];
#pragma unroll
    for (int rt = 0; rt < 4; ++rt) rr[rt] = (f4){b, b, b, b};
  }
  {
    const float b = brz[128 + col];
#pragma unroll
    for (int rt = 0; rt < 4; ++rt) rz[rt] = (f4){b, b, b, b};
  }
  {
    bf8 W[4];
#pragma unroll
    for (int c = 0; c < 4; ++c) W[c] = wh[(w * 12 + 8 + c) * 64 + lane];
#pragma unroll
    for (int c = 0; c < 4; ++c)
#pragma unroll
      for (int rt = 0; rt < 4; ++rt) t2[rt] = MFMA(ah[rt][c], W[c], t2[rt]);
  }
  {
    bf8 W[4];
#pragma unroll
    for (int c = 0; c < 4; ++c) W[c] = wh[(w * 12 + 0 + c) * 64 + lane];
#pragma unroll
    for (int c = 0; c < 4; ++c)
#pragma unroll
      for (int rt = 0; rt < 4; ++rt) rr[rt] = MFMA(ah[rt][c], W[c], rr[rt]);
  }
  {
    bf8 W[4];
#pragma unroll
    for (int c = 0; c < 4; ++c) W[c] = wh[(w * 12 + 4 + c) * 64 + lane];
#pragma unroll
    for (int c = 0; c < 4; ++c)
#pragma unroll
      for (int rt = 0; rt < 4; ++rt) rz[rt] = MFMA(ah[rt][c], W[c], rz[rt]);
  }
}

// GRU x-part + epilogue: 12 x-MFMAs, gate nonlinearities, blend.
__device__ __forceinline__ void gru_xepi(const short* xs, const short* hsrc,
                                         const short* wiP, const float* bi2v,
                                         int lane, int w,
                                         f4* t2, f4* rr, f4* rz, f4* hv) {
  const int l15 = lane & 15, q = lane >> 4;
  const int col = w * 16 + l15;
  bf8 ax[4];
#pragma unroll
  for (int rt = 0; rt < 4; ++rt)
    ax[rt] = *(const bf8*)(xs + (rt * 16 + l15) * PSLD + q * 8);
  const bf8* wi = (const bf8*)wiP;
  const bf8 Wr = wi[(w * 3 + 0) * 64 + lane];
  const bf8 Wz = wi[(w * 3 + 1) * 64 + lane];
  const bf8 Wn = wi[(w * 3 + 2) * 64 + lane];
#pragma unroll
  for (int rt = 0; rt < 4; ++rt) rr[rt] = MFMA(ax[rt], Wr, rr[rt]);
  const float b2 = bi2v[col];
#pragma unroll
  for (int rt = 0; rt < 4; ++rt)
#pragma unroll
    for (int j = 0; j < 4; ++j)
      t2[rt][j] = t2[rt][j] * sigmoidf_(rr[rt][j]) + b2;  // r*(h@wh2+bh2)+bi2
#pragma unroll
  for (int rt = 0; rt < 4; ++rt) t2[rt] = MFMA(ax[rt], Wn, t2[rt]);
#pragma unroll
  for (int rt = 0; rt < 4; ++rt) rz[rt] = MFMA(ax[rt], Wz, rz[rt]);
  // h' = n + z*(h - n)
#pragma unroll
  for (int rt = 0; rt < 4; ++rt)
#pragma unroll
    for (int j = 0; j < 4; ++j) {
      const float hc = bf2f(hsrc[(rt * 16 + q * 4 + j) * SH + col]);
      const float zz = sigmoidf_(rz[rt][j]);
      const float nn = tanhf_(t2[rt][j]);
      hv[rt][j] = nn + zz * (hc - nn);
    }
}

// pred for row-tile w (waves 0..3): pred = h@h2o + b; softmax;
// pred -> LDS spred (fp32), probs -> LDS pstk.  (verbatim r7 green body)
__device__ __forceinline__ void pred_node16(const short* hsrc,
                                            const short* h2oP,
                                            const float* bo,
                                            float* spred, short* pdst,
                                            int lane, int w) {
  const int l15 = lane & 15, q = lane >> 4;
  bf8 a[4];
#pragma unroll
  for (int c = 0; c < 4; ++c)
    a[c] = *(const bf8*)(hsrc + (w * 16 + l15) * SH + c * 32 + q * 8);
  const bf8* bw = (const bf8*)h2oP;
  bf8 W[8];
#pragma unroll
  for (int f = 0; f < 8; ++f) W[f] = bw[f * 64 + lane];
  f4 p[2];
#pragma unroll
  for (int nt = 0; nt < 2; ++nt) {
    const float b = bo[nt * 16 + l15];
    f4 acc = (f4){b, b, b, b};
#pragma unroll
    for (int c = 0; c < 4; ++c) acc = MFMA(a[c], W[nt * 4 + c], acc);
    p[nt] = acc;
  }
#pragma unroll
  for (int j = 0; j < 4; ++j) {
    const float v0 = p[0][j], v1 = p[1][j];
    float mx = fmaxf(v0, v1);
#pragma unroll
    for (int s = 1; s < 16; s <<= 1) mx = fmaxf(mx, __shfl_xor(mx, s));
    const float e0 = __expf(v0 - mx), e1 = __expf(v1 - mx);
    float ss = e0 + e1;
#pragma unroll
    for (int s = 1; s < 16; s <<= 1) ss += __shfl_xor(ss, s);
    const float inv = rcp_(ss);
    const int row = w * 16 + q * 4 + j;
    spred[row * 32 + l15] = v0;
    spred[row * 32 + 16 + l15] = v1;
    pdst[row * PSLD + l15] = f2bf(e0 * inv);
    pdst[row * PSLD + 16 + l15] = f2bf(e1 * inv);
  }
}

// preorder schedule, depth 4: type 0=root, 1=left child (gru_a), 2=right child
__device__ const unsigned char d_TYPE[31] =
    {0,1,1,1,1,2,2,1,2,2,1,1,2,2,1,2,2,1,1,1,2,2,1,2,2,1,1,2,2,1,2};
__device__ const unsigned char d_LVL[31] =
    {0,1,2,3,4,4,3,4,4,2,3,4,4,3,4,4,1,2,3,4,4,3,4,4,2,3,4,4,3,4,4};

// ---------------- the fused tree kernel -------------------------------------
__global__ __launch_bounds__(512, 2) void k_tree(
    const float* __restrict__ zf, const short* __restrict__ pw,
    const float* __restrict__ z2hb, const float* __restrict__ abi,
    const float* __restrict__ abh, const float* __restrict__ fbi,
    const float* __restrict__ fbh, const float* __restrict__ uab,
    const float* __restrict__ ufb, const float* __restrict__ h2ob,
    float* __restrict__ out) {
  __shared__ __align__(16) short hstk[5 * ROWS * SH];   // 87040 B
  __shared__ __align__(16) short hfb[ROWS * SH];        // 17408 B (overlaid: spred)
  __shared__ __align__(16) short pstk[5 * ROWS * PSLD]; // 25600 B
  __shared__ float bias[BIAS_N];                        // 5248 B => 135296 B total
  float* spred = (float*)hfb;                           // 8192 B, lifetime-disjoint
  const int lane = threadIdx.x & 63;
  const int w = threadIdx.x >> 6;        // 8 waves, wave w owns nt tile w
  const int l15 = lane & 15, q = lane >> 4;
  const int col = w * 16 + l15;
  const int r0 = blockIdx.x * ROWS;

  // bias preload: pre-summed where the algorithm always sums them
  for (int t = threadIdx.x; t < BIAS_N; t += 512) {
    float v;
    if (t < 256)       v = abi[t] + abh[t];
    else if (t < 384)  v = abh[t];           // abh gate2
    else if (t < 512)  v = abi[t - 128];     // abi gate2
    else if (t < 768)  v = fbi[t - 512] + fbh[t - 512];
    else if (t < 896)  v = fbh[t - 512];
    else if (t < 1024) v = fbi[t - 640];
    else if (t < 1152) v = uab[t - 1024] + ufb[t - 1024];
    else if (t < 1280) v = z2hb[t - 1152];
    else               v = h2ob[t - 1280];
    bias[t] = v;
  }
  __syncthreads();

  // root: h_in[0] = z @ z2h + b  (z read as f32, scalar f2bf in-register)
  {
    const bf8* wz = (const bf8*)(pw + PW_Z2H);
    const bf8 W0 = wz[(w * 2 + 0) * 64 + lane];
    const bf8 W1 = wz[(w * 2 + 1) * 64 + lane];
    const float b = bias[BZ2H + col];
    f4 hv[4];
#pragma unroll
    for (int rt = 0; rt < 4; ++rt) {
      const float* zr = zf + (size_t)(r0 + rt * 16 + l15) * 64 + q * 8;
      union { short s[8]; bf8 v; } A0, A1;
      {
        const f4 x0 = *(const f4*)zr, x1 = *(const f4*)(zr + 4);
#pragma unroll
        for (int j = 0; j < 4; ++j) { A0.s[j] = f2bf(x0[j]); A0.s[4 + j] = f2bf(x1[j]); }
        const f4 y0 = *(const f4*)(zr + 32), y1 = *(const f4*)(zr + 36);
#pragma unroll
        for (int j = 0; j < 4; ++j) { A1.s[j] = f2bf(y0[j]); A1.s[4 + j] = f2bf(y1[j]); }
      }
      f4 acc = (f4){b, b, b, b};
      acc = MFMA(A0.v, W0, acc);
      acc = MFMA(A1.v, W1, acc);
      hv[rt] = acc;
    }
    store_slice(hv, hstk, lane, w);
  }
  __syncthreads();

#pragma unroll 1
  for (int i = 0; i < 31; ++i) {
    const int t = d_TYPE[i];
    const int L = d_LVL[i];
    short* hcur = hstk + L * ROWS * SH;
    short* pcur = pstk + L * ROWS * PSLD;

    if (t == 2) {
      // h_f = gru_f(probs_sib, h_sib) — both inputs ready at iteration entry
      f4 ft2[4], frr[4], frz[4], hf[4];
      gru_hpart(hcur, pw + PW_FWH, bias + BF_RZ, bias + BF_BH2, lane, w,
                ft2, frr, frz);
      gru_xepi(pcur, hcur, pw + PW_FWI, bias + BF_BI2, lane, w,
               ft2, frr, frz, hf);
      store_slice(hf, hfb, lane, w);
      __syncthreads();
      // h2 = tanh(h_f@uf + h_par@ua + b)
      const short* hpar = hstk + (L - 1) * ROWS * SH;
      const bf8* uf = (const bf8*)(pw + PW_UF);
      const bf8* ua = (const bf8*)(pw + PW_UA);
      bf8 Wf[4], Wa[4];
#pragma unroll
      for (int c = 0; c < 4; ++c) {
        Wf[c] = uf[(w * 4 + c) * 64 + lane];
        Wa[c] = ua[(w * 4 + c) * 64 + lane];
      }
      const float b = bias[BU + col];
      f4 hv[4];
#pragma unroll
      for (int rt = 0; rt < 4; ++rt) {
        f4 acc = (f4){b, b, b, b};
#pragma unroll
        for (int c = 0; c < 4; ++c) {
          const bf8 af = *(const bf8*)(hfb + (rt * 16 + l15) * SH + c * 32 + q * 8);
          const bf8 ap = *(const bf8*)(hpar + (rt * 16 + l15) * SH + c * 32 + q * 8);
          acc = MFMA(af, Wf[c], acc);
          acc = MFMA(ap, Wa[c], acc);
        }
#pragma unroll
        for (int j = 0; j < 4; ++j) acc[j] = tanhf_(acc[j]);
        hv[rt] = acc;
      }
      store_slice(hv, hcur, lane, w);
      __syncthreads();
    }

    // phase A: gru_a h-part (all waves, internal nodes) overlaps pred (w<4)
    f4 t2[4], rr[4], rz[4];
    if (L < 4)
      gru_hpart(hcur, pw + PW_AWH, bias + BA_RZ, bias + BA_BH2, lane, w,
                t2, rr, rz);
    if (w < 4)
      pred_node16(hcur, pw + PW_H2O, bias + BH2O, spred, pcur, lane, w);
    __syncthreads();

    // phase B: dump pred (coalesced) ∥ gru_a x-part + epilogue + store
    {
      const f4 v = *(const f4*)(spred + threadIdx.x * 4);
      __builtin_nontemporal_store(
          v, (f4*)(out + (size_t)i * BB * OO + (size_t)r0 * OO) + threadIdx.x);
    }
    if (L < 4) {
      f4 hv[4];
      gru_xepi(pcur, hcur, pw + PW_AWI, bias + BA_BI2, lane, w,
               t2, rr, rz, hv);
      store_slice(hv, hstk + (L + 1) * ROWS * SH, lane, w);
    }
    // barrier also protects spred (overlaid on hfb) against next node's writes
    __syncthreads();
  }
}

// ---------------- host ------------------------------------------------------
extern "C" void kernel_launch(void* const* d_in, const int* in_sizes, int n_in,
                              void* d_out, int out_size, void* d_ws, size_t ws_size,
                              hipStream_t stream) {
  const float* z    = (const float*)d_in[0];
  const float* z2hw = (const float*)d_in[1];
  const float* z2hb = (const float*)d_in[2];
  const float* h2ow = (const float*)d_in[3];
  const float* h2ob = (const float*)d_in[4];
  const float* awi  = (const float*)d_in[5];
  const float* abi  = (const float*)d_in[6];
  const float* awh  = (const float*)d_in[7];
  const float* abh  = (const float*)d_in[8];
  const float* fwi  = (const float*)d_in[9];
  const float* fbi  = (const float*)d_in[10];
  const float* fwh  = (const float*)d_in[11];
  const float* fbh  = (const float*)d_in[12];
  const float* uaw  = (const float*)d_in[13];
  const float* uab  = (const float*)d_in[14];
  const float* ufw  = (const float*)d_in[15];
  const float* ufb  = (const float*)d_in[16];

  float* out = (float*)d_out;
  short* ws  = (short*)d_ws;

  k_repack<<<(PW_END + 255) / 256, 256, 0, stream>>>(
      z2hw, awi, awh, fwi, fwh, uaw, ufw, h2ow, ws);

  k_tree<<<BB / ROWS, 512, 0, stream>>>(
      z, ws, z2hb, abi, abh, fbi, fbh, uab, ufb, h2ob, out);
}